// Round 2
// baseline (248.269 us; speedup 1.0000x reference)
//
#include <hip/hip_runtime.h>

// Fan Model nonlinear mixing.
// E: (1, 224, 12) fp32, A: (1, 12, 512, 512) fp32 -> out: (1, 224, 512, 512) fp32.
// Identity: sum_{i<j} E_i E_j a_i a_j = 0.5*((sum E_p a_p)^2 - sum E_p^2 a_p^2)
// => out[b,x] = L + 0.5*(L*L - Q), L = dot(E[b],a), Q = dot(E[b]^2, a^2).
//
// R4 (resubmit after infra failure): key algebraic observation:
// E_p^2 * a_p^2 = (E_p * a_p)^2, so per term
//   t = e*a; L += t; Q = fma(t,t,Q)
// needs NO a^2 register array, NO E2 scratch, NO prep kernel.
// Freed VGPRs spent on float4 vectorization (dwordx4 load/store, 1KB/wave)
// and unroll-4 band loop (4 store-data register sets in flight -> no
// per-band vmcnt drain while streaming stores).

#define NP 12
#define NB 224
#define HW (512 * 512)
#define BPG 28        // bands per group (NB / NGRP)
#define NGRP 8        // grid.y
#define BLOCK 256

typedef float vfloat4 __attribute__((ext_vector_type(4)));

__global__ __launch_bounds__(BLOCK) void fan_mix(const float* __restrict__ E,
                                                 const float* __restrict__ A,
                                                 float* __restrict__ out) {
    const int x4 = blockIdx.x * BLOCK + threadIdx.x;   // float4 (pixel-quad) index
    const int b0 = blockIdx.y * BPG;

    const vfloat4* __restrict__ A4 = (const vfloat4*)A;
    vfloat4* __restrict__ O4 = (vfloat4*)out;

    // Per-pixel-quad abundances in registers: 12 x float4 = 48 VGPR.
    // Coalesced dwordx4: 1 KB/wave per p.
    vfloat4 a[NP];
#pragma unroll
    for (int p = 0; p < NP; ++p) {
        a[p] = A4[(size_t)p * (HW / 4) + x4];
    }

    // Band loop: E indices are wave-uniform -> scalar loads via constant cache.
    // unroll 4 keeps 4 independent {L,Q,r} register sets so stores stream
    // without forcing vmcnt drains on register reuse.
#pragma unroll 4
    for (int b = b0; b < b0 + BPG; ++b) {
        vfloat4 L = 0.f, Q = 0.f;
#pragma unroll
        for (int p = 0; p < NP; ++p) {
            float e = E[b * NP + p];
            vfloat4 t = e * a[p];
            L += t;                       // v_add x4 (or fmac after contraction)
            Q += t * t;                   // v_fma x4: Q = fma(t,t,Q)
        }
        // r = L + 0.5*(L^2 - Q): two fma per lane-element.
        vfloat4 r = L + 0.5f * (L * L - Q);
        // Streaming store: out is write-once, never re-read -> nontemporal
        // keeps A resident in L2/L3.
        __builtin_nontemporal_store(r, &O4[(size_t)b * (HW / 4) + x4]);
    }
}

extern "C" void kernel_launch(void* const* d_in, const int* in_sizes, int n_in,
                              void* d_out, int out_size, void* d_ws, size_t ws_size,
                              hipStream_t stream) {
    const float* E = (const float*)d_in[0];   // (1, 224, 12)
    const float* A = (const float*)d_in[1];   // (1, 12, 512, 512)
    float* out = (float*)d_out;               // (1, 224, 512, 512)

    dim3 grid(HW / (4 * BLOCK), NGRP);        // (256, 8) = 2048 blocks
    fan_mix<<<grid, BLOCK, 0, stream>>>(E, A, out);
}

// Round 3
// 244.018 us; speedup vs baseline: 1.0174x; 1.0174x over previous
//
#include <hip/hip_runtime.h>

// Fan Model nonlinear mixing.
// E: (1, 224, 12) fp32, A: (1, 12, 512, 512) fp32 -> out: (1, 224, 512, 512) fp32.
// Identity: sum_{i<j} E_i E_j a_i a_j = 0.5*((sum E_p a_p)^2 - sum E_p^2 a_p^2)
// => out[b,x] = L + 0.5*(L*L - Q), L = dot(E[b],a), Q = dot(E[b]^2, a^2).
//
// R5: single-variable change vs R4: PLAIN stores instead of
// __builtin_nontemporal_store. Evidence: harness fill kernel sustains
// 6.35 TB/s on the same output buffer with cached stores, while fan_mix
// only reaches ~2.4 TB/s effective write BW with nt stores. nt bypasses
// L2 write-combining; A (12.6 MB) survives in the 256 MB L3 regardless,
// so the nt hint protects nothing.
//
// Kept from R4: t = e*a; L += t; Q = fma(t,t,Q) (no a^2 array, no E2
// scratch, no prep kernel); float4 dwordx4 loads/stores; unroll-4 band loop.

#define NP 12
#define NB 224
#define HW (512 * 512)
#define BPG 28        // bands per group (NB / NGRP)
#define NGRP 8        // grid.y
#define BLOCK 256

typedef float vfloat4 __attribute__((ext_vector_type(4)));

__global__ __launch_bounds__(BLOCK) void fan_mix(const float* __restrict__ E,
                                                 const float* __restrict__ A,
                                                 float* __restrict__ out) {
    const int x4 = blockIdx.x * BLOCK + threadIdx.x;   // float4 (pixel-quad) index
    const int b0 = blockIdx.y * BPG;

    const vfloat4* __restrict__ A4 = (const vfloat4*)A;
    vfloat4* __restrict__ O4 = (vfloat4*)out;

    // Per-pixel-quad abundances in registers: 12 x float4 = 48 VGPR.
    // Coalesced dwordx4: 1 KB/wave per p.
    vfloat4 a[NP];
#pragma unroll
    for (int p = 0; p < NP; ++p) {
        a[p] = A4[(size_t)p * (HW / 4) + x4];
    }

    // Band loop: E indices are wave-uniform -> scalar loads via constant cache.
    // unroll 4 keeps 4 independent {L,Q,r} register sets in flight.
#pragma unroll 4
    for (int b = b0; b < b0 + BPG; ++b) {
        vfloat4 L = 0.f, Q = 0.f;
#pragma unroll
        for (int p = 0; p < NP; ++p) {
            float e = E[b * NP + p];
            vfloat4 t = e * a[p];
            L += t;                       // v_add x4
            Q += t * t;                   // v_fma x4: Q = fma(t,t,Q)
        }
        // r = L + 0.5*(L^2 - Q): two fma per lane-element.
        vfloat4 r = L + 0.5f * (L * L - Q);
        // R5: plain cached store — let L2 write-combine and evict full
        // lines (the path the 6.35 TB/s fill kernel uses).
        O4[(size_t)b * (HW / 4) + x4] = r;
    }
}

extern "C" void kernel_launch(void* const* d_in, const int* in_sizes, int n_in,
                              void* d_out, int out_size, void* d_ws, size_t ws_size,
                              hipStream_t stream) {
    const float* E = (const float*)d_in[0];   // (1, 224, 12)
    const float* A = (const float*)d_in[1];   // (1, 12, 512, 512)
    float* out = (float*)d_out;               // (1, 224, 512, 512)

    dim3 grid(HW / (4 * BLOCK), NGRP);        // (256, 8) = 2048 blocks
    fan_mix<<<grid, BLOCK, 0, stream>>>(E, A, out);
}

// Round 4
// 241.408 us; speedup vs baseline: 1.0284x; 1.0108x over previous
//
#include <hip/hip_runtime.h>

// Fan Model nonlinear mixing.
// E: (1, 224, 12) fp32, A: (1, 12, 512, 512) fp32 -> out: (1, 224, 512, 512) fp32.
// Identity: sum_{i<j} E_i E_j a_i a_j = 0.5*((sum E_p a_p)^2 - sum E_p^2 a_p^2)
// => out[b,x] = L + 0.5*(L*L - Q), L = dot(E[b],a), Q = dot(E[b]^2, a^2).
//
// R6: attack WRITE FRAGMENTATION. R3/R4/R5 (x2/x4, nt/cached) all ~identical
// => bottleneck is the write address pattern: 28 chunks/wave at 1 MiB stride,
// only 4 KB contiguous per block per band, adjacent chunks on different XCD
// L2s at uncorrelated times -> no write merging anywhere. Fill kernel proves
// 6.35 TB/s with sequential streams at 10% occupancy; we see ~2.6 TB/s.
// Changes:
//   1. PQ=2 quads/thread -> 8 KB contiguous per block per band.
//   2. XCD-chunked blockIdx.x swizzle (exact: 128 % 8 == 0): 16 consecutive
//      logical x-blocks share one XCD, so each band's 128 KB pixel window
//      drains through ONE L2 -> compact write-back window -> DRAM row merge.
// Kept: t=e*a; L+=t; Q=fma(t,t,Q); float4 loads/stores; plain cached stores.

#define NP 12
#define NB 224
#define HW (512 * 512)
#define NQ (HW / 4)        // 65536 float4 quads per plane
#define BPG 28             // bands per y-group
#define NGRP 8             // grid.y
#define BLOCK 256
#define PQ 2               // quads per thread
#define QPB (BLOCK * PQ)   // 512 quads per block
#define GX (NQ / QPB)      // 128 x-blocks
#define NXCD 8

typedef float vfloat4 __attribute__((ext_vector_type(4)));

__global__ __launch_bounds__(BLOCK) void fan_mix(const float* __restrict__ E,
                                                 const float* __restrict__ A,
                                                 float* __restrict__ out) {
    // XCD-chunked swizzle: dispatch linear id = y*GX + gx; GX%8==0 so
    // xcd = gx % 8 for every y. Map so logical blocks 16k..16k+15 all sit
    // on xcd k -> contiguous 128 KB write window per XCD per band.
    const int gx = blockIdx.x;                                  // 0..127
    const int lx = (gx % NXCD) * (GX / NXCD) + gx / NXCD;       // logical x
    const int q0 = lx * QPB + threadIdx.x;                      // first quad
    const int b0 = blockIdx.y * BPG;

    const vfloat4* __restrict__ A4 = (const vfloat4*)A;
    vfloat4* __restrict__ O4 = (vfloat4*)out;

    // Two quads per thread: 24 x float4 = 96 VGPR of abundances.
    // Loads coalesced: wave covers [q0base, q0base+1KB) and [+4KB, +5KB).
    vfloat4 a0[NP], a1[NP];
#pragma unroll
    for (int p = 0; p < NP; ++p) {
        a0[p] = A4[(size_t)p * NQ + q0];
        a1[p] = A4[(size_t)p * NQ + q0 + BLOCK];
    }

    // Band loop: E loads are wave-uniform -> scalar/constant cache.
    // unroll 2 x 2 quads = 4 independent {L,Q,r} sets in flight.
#pragma unroll 2
    for (int b = b0; b < b0 + BPG; ++b) {
        vfloat4 L0 = 0.f, Q0 = 0.f, L1 = 0.f, Q1 = 0.f;
#pragma unroll
        for (int p = 0; p < NP; ++p) {
            float e = E[b * NP + p];
            vfloat4 t0 = e * a0[p];
            vfloat4 t1 = e * a1[p];
            L0 += t0;  Q0 += t0 * t0;
            L1 += t1;  Q1 += t1 * t1;
        }
        vfloat4 r0 = L0 + 0.5f * (L0 * L0 - Q0);
        vfloat4 r1 = L1 + 0.5f * (L1 * L1 - Q1);
        const size_t o = (size_t)b * NQ + q0;
        O4[o] = r0;
        O4[o + BLOCK] = r1;
    }
}

extern "C" void kernel_launch(void* const* d_in, const int* in_sizes, int n_in,
                              void* d_out, int out_size, void* d_ws, size_t ws_size,
                              hipStream_t stream) {
    const float* E = (const float*)d_in[0];   // (1, 224, 12)
    const float* A = (const float*)d_in[1];   // (1, 12, 512, 512)
    float* out = (float*)d_out;               // (1, 224, 512, 512)

    dim3 grid(GX, NGRP);                      // (128, 8) = 1024 blocks
    fan_mix<<<grid, BLOCK, 0, stream>>>(E, A, out);
}